// Round 7
// baseline (150.919 us; speedup 1.0000x reference)
//
#include <hip/hip_runtime.h>

typedef __attribute__((ext_vector_type(8))) short bf16x8;
typedef __attribute__((ext_vector_type(4))) float f32x4;

// ---------------------------------------------------------------------------
// f32 -> bf16 round-to-nearest-even
__device__ __forceinline__ unsigned short f2bf(float x) {
    unsigned u = __float_as_uint(x);
    u += 0x7fffu + ((u >> 16) & 1u);
    return (unsigned short)(u >> 16);
}

// Fused slice + convert + mask-zero for BOTH inputs (one launch).
__global__ void conv_kernel(const float* __restrict__ im, const int* __restrict__ iml,
                            const float* __restrict__ ss, const int* __restrict__ sl,
                            unsigned short* __restrict__ Ad, unsigned short* __restrict__ Bd)
{
    int bid = blockIdx.x;
    const float* src; const int* len; unsigned short* dst; int rawL, adj;
    if (bid < 8192) { src = im; len = iml; dst = Ad; rawL = 65; adj = -1; }
    else { bid -= 8192; src = ss; len = sl; dst = Bd; rawL = 67; adj = -3; }
    int m = bid;
    int c = threadIdx.x << 2;
    int b = m >> 6;
    int i = m & 63;
    int lim = len[b] + adj;
    float4 v;
    if (i < lim) {
        v = *(const float4*)(src + ((size_t)(b * rawL + 1 + i) << 10) + c);
    } else {
        v = make_float4(0.f, 0.f, 0.f, 0.f);
    }
    ushort4 o;
    o.x = f2bf(v.x); o.y = f2bf(v.y); o.z = f2bf(v.z); o.w = f2bf(v.w);
    *(ushort4*)(dst + ((size_t)m << 10) + c) = o;
}

// ---------------------------------------------------------------------------
__device__ __forceinline__ void gload_lds16(const void* g, void* l) {
    __builtin_amdgcn_global_load_lds((const __attribute__((address_space(1))) void*)g,
                                     (__attribute__((address_space(3))) void*)l,
                                     16, 0, 0);
}

// 256x256 tile, BK=64, 8 waves (2M x 4N), per-wave 128x64 output, 16x16x32 MFMA.
// Fine-phase m201-style schedule: 4 phases/tile, each = {<=12 ds_reads for THIS
// phase, staging burst, 16 MFMA, barrier}. Tile t+1 staged early (A @ t.p0,
// B @ t.p1) so the t+1 entry gate drains only >=3-phase-old loads (free).
// Compiler emits counted lgkmcnt between reads and MFMA (no explicit lgkm).
// Fused wave-local reduction: aggr[b,t] = sum_j max_i C_cell.
__global__ void __launch_bounds__(512) gemm_aggr_kernel(const unsigned short* __restrict__ A,
                                                        const unsigned short* __restrict__ B,
                                                        float* __restrict__ aggr)
{
    __shared__ __align__(16) unsigned short As[2][2][128 * 64];   // [buf][half] 64 KiB
    __shared__ __align__(16) unsigned short Bs[2][2][128 * 64];   // [buf][half] 64 KiB

    const int tid  = threadIdx.x;
    const int lane = tid & 63;
    const int wid  = tid >> 6;        // 0..7
    const int wr   = wid >> 2;        // 0..1 : 128-row half of BM
    const int wc   = wid & 3;         // 0..3 : 64-col quarter of BN
    const int tm   = blockIdx.y;      // 0..31
    const int tn   = blockIdx.x;      // 0..31

    const int r15 = lane & 15;
    const int g4  = lane >> 4;        // 0..3
    const int swz = r15 & 7;

    // Staging: per half 2 rounds of 64 rows x 64 cols (8 KB = 512 thr x 16 B).
    // LDS dest linear; global source chunk pre-swizzled (both-sides XOR).
    const int srow   = tid >> 3;                  // 0..63
    const int schunk = (tid & 7) ^ (srow & 7);
    const unsigned short* gA_t = A + ((size_t)(tm * 256 + srow) << 10) + schunk * 8;
    const unsigned short* gB_t = B + ((size_t)(tn * 256 + srow) << 10) + schunk * 8;

#define STAGE_A(kt, h, r) gload_lds16(gA_t + (((size_t)((h) * 128 + (r) * 64)) << 10) + (kt) * 64, \
                                      (char*)As[(kt) & 1][h] + (r) * 8192 + tid * 16)
#define STAGE_B(kt, h, r) gload_lds16(gB_t + (((size_t)((h) * 128 + (r) * 64)) << 10) + (kt) * 64, \
                                      (char*)Bs[(kt) & 1][h] + (r) * 8192 + tid * 16)

    f32x4 acc[4][2][4];   // [32-row quadrant][mi][ni]
#pragma unroll
    for (int p = 0; p < 4; ++p)
#pragma unroll
        for (int mi = 0; mi < 2; ++mi)
#pragma unroll
            for (int ni = 0; ni < 4; ++ni)
                acc[p][mi][ni] = (f32x4){0.f, 0.f, 0.f, 0.f};

    // Prologue: stage tile 0 fully (8 gloads).
    STAGE_A(0, 0, 0); STAGE_A(0, 0, 1); STAGE_A(0, 1, 0); STAGE_A(0, 1, 1);
    STAGE_B(0, 0, 0); STAGE_B(0, 0, 1); STAGE_B(0, 1, 0); STAGE_B(0, 1, 1);

    const int BrowO = ((wc & 1) * 64 + r15) * 128;   // byte row base within B half
    const int ArowO = r15 * 128;                     // + (q*32 + mi*16)*128
    const int ch0 = (g4 ^ swz) * 16;
    const int ch1 = ((4 + g4) ^ swz) * 16;

    bf16x8 bg[4][2];

#define LOAD_AQ(AF, Ab, Q)                                                  \
    _Pragma("unroll")                                                       \
    for (int mi = 0; mi < 2; ++mi) {                                        \
        const int o_ = ArowO + ((Q) * 32 + mi * 16) * 128;                  \
        AF[mi][0] = *(const bf16x8*)((Ab) + o_ + ch0);                      \
        AF[mi][1] = *(const bf16x8*)((Ab) + o_ + ch1);                      \
    }

#define MFMA_Q(Q, AF)                                                      \
    __builtin_amdgcn_s_setprio(1);                                          \
    _Pragma("unroll")                                                       \
    for (int mi = 0; mi < 2; ++mi)                                          \
      _Pragma("unroll")                                                     \
      for (int ni = 0; ni < 4; ++ni) {                                      \
        acc[Q][mi][ni] = __builtin_amdgcn_mfma_f32_16x16x32_bf16(           \
            AF[mi][0], bg[ni][0], acc[Q][mi][ni], 0, 0, 0);                 \
        acc[Q][mi][ni] = __builtin_amdgcn_mfma_f32_16x16x32_bf16(           \
            AF[mi][1], bg[ni][1], acc[Q][mi][ni], 0, 0, 0);                 \
      }                                                                     \
    __builtin_amdgcn_s_setprio(0);

    for (int kt = 0; kt < 16; ++kt) {
        const char* Ab = (const char*)As[kt & 1][wr];
        const char* Bb = (const char*)Bs[kt & 1][wc >> 1];
        bf16x8 af[2][2];

        // ---- phase 0 : quadrant 0 (+ B for whole tile) ----
        asm volatile("s_waitcnt vmcnt(0)" ::: "memory");   // drains >=3-phase-old loads only
        __builtin_amdgcn_s_barrier();
        __builtin_amdgcn_sched_barrier(0);
#pragma unroll
        for (int ni = 0; ni < 4; ++ni) {
            bg[ni][0] = *(const bf16x8*)(Bb + BrowO + ni * 2048 + ch0);
            bg[ni][1] = *(const bf16x8*)(Bb + BrowO + ni * 2048 + ch1);
        }
        LOAD_AQ(af, Ab, 0)
        if (kt < 15) { STAGE_A(kt + 1, 0, 0); STAGE_A(kt + 1, 0, 1);
                       STAGE_A(kt + 1, 1, 0); STAGE_A(kt + 1, 1, 1); }
        MFMA_Q(0, af)
        __builtin_amdgcn_s_barrier();

        // ---- phase 1 : quadrant 1 ----
        LOAD_AQ(af, Ab, 1)
        if (kt < 15) { STAGE_B(kt + 1, 0, 0); STAGE_B(kt + 1, 0, 1);
                       STAGE_B(kt + 1, 1, 0); STAGE_B(kt + 1, 1, 1); }
        MFMA_Q(1, af)
        __builtin_amdgcn_s_barrier();

        // ---- phase 2 : quadrant 2 ----
        LOAD_AQ(af, Ab, 2)
        MFMA_Q(2, af)
        __builtin_amdgcn_s_barrier();

        // ---- phase 3 : quadrant 3 (trailing fence = next tile's gate+barrier) ----
        LOAD_AQ(af, Ab, 3)
        MFMA_Q(3, af)
    }
#undef STAGE_A
#undef STAGE_B
#undef LOAD_AQ
#undef MFMA_Q

    // Fused reduction per 64x64 (b,t) cell. C/D: col=lane&15, row=(lane>>4)*4+reg.
#pragma unroll
    for (int h = 0; h < 2; ++h) {
        float cm[4];
#pragma unroll
        for (int ni = 0; ni < 4; ++ni) {
            float m = acc[h * 2][0][ni][0];
#pragma unroll
            for (int pp = 0; pp < 2; ++pp)
#pragma unroll
                for (int mi = 0; mi < 2; ++mi)
#pragma unroll
                    for (int r = 0; r < 4; ++r)
                        m = fmaxf(m, acc[h * 2 + pp][mi][ni][r]);
            m = fmaxf(m, __shfl_xor(m, 16));
            m = fmaxf(m, __shfl_xor(m, 32));
            cm[ni] = m;
        }
        float s = cm[0] + cm[1] + cm[2] + cm[3];
        s += __shfl_xor(s, 1);
        s += __shfl_xor(s, 2);
        s += __shfl_xor(s, 4);
        s += __shfl_xor(s, 8);
        if (lane == 0) {
            int b = tm * 4 + wr * 2 + h;
            int t = tn * 4 + wc;
            aggr[b * 128 + t] = s;
        }
    }
}

// ---------------------------------------------------------------------------
__global__ void loss_kernel(const float* __restrict__ aggr, float* __restrict__ out)
{
    __shared__ float red[128];
    const int x = threadIdx.x;
    const float diag = aggr[x * 128 + x];
    float mrow = 0.f, mcol = 0.f;
    for (int y = 0; y < 128; ++y) {
        if (y == x) continue;
        float a_xy = aggr[x * 128 + y];
        float a_yx = aggr[y * 128 + x];
        mrow = fmaxf(mrow, 0.2f + a_xy - diag);
        mcol = fmaxf(mcol, 0.2f + a_yx - diag);
    }
    red[x] = mrow + mcol;
    __syncthreads();
    if (x == 0) {
        float s = 0.f;
        for (int i = 0; i < 128; ++i) s += red[i];
        *out = s;
    }
}

// ---------------------------------------------------------------------------
extern "C" void kernel_launch(void* const* d_in, const int* in_sizes, int n_in,
                              void* d_out, int out_size, void* d_ws, size_t ws_size,
                              hipStream_t stream)
{
    const float* im_set = (const float*)d_in[0];
    const float* s_seq  = (const float*)d_in[1];
    const int*   im_len = (const int*)d_in[2];
    const int*   s_len  = (const int*)d_in[3];
    float* out = (float*)d_out;

    unsigned short* Abf = (unsigned short*)d_ws;                           // 16 MiB
    unsigned short* Bbf = (unsigned short*)((char*)d_ws + (16u << 20));    // 16 MiB
    float*          agg = (float*)((char*)d_ws + (32u << 20));             // 64 KiB

    conv_kernel<<<16384, 256, 0, stream>>>(im_set, im_len, s_seq, s_len, Abf, Bbf);

    gemm_aggr_kernel<<<dim3(32, 32), 512, 0, stream>>>(Abf, Bbf, agg);

    loss_kernel<<<1, 128, 0, stream>>>(agg, out);
}